// Round 6
// baseline (3818.569 us; speedup 1.0000x reference)
//
#include <hip/hip_runtime.h>
#include <hip/hip_fp16.h>

#define T_LEN 1024
#define E_DIM 300
#define H_DIM 512
#define D_DIM 1024
#define K_TAGS 12
#define G4 2048   // 4*H

typedef __attribute__((ext_vector_type(8))) short short8x;  // 8 bf16
typedef __attribute__((ext_vector_type(4))) float f32x4;

static __device__ __forceinline__ float frcp(float x){ return __builtin_amdgcn_rcpf(x); }
static __device__ __forceinline__ float sigm(float x){ return frcp(1.f + __expf(-x)); }
// overflow-safe fast tanh
static __device__ __forceinline__ float ftanh(float x){
  const float e = __expf(2.f * fabsf(x));
  const float t = 1.f - 2.f * frcp(e + 1.f);
  return copysignf(t, x);
}
// f32 -> bf16 round-to-nearest-even
static __device__ __forceinline__ unsigned short f2b(float f){
  unsigned u = __float_as_uint(f);
  return (unsigned short)((u + 0x7fffu + ((u >> 16) & 1u)) >> 16);
}
static __device__ __forceinline__ uint4 pack8(const float* s){
  uint4 o;
  o.x = (unsigned)f2b(s[0]) | ((unsigned)f2b(s[1]) << 16);
  o.y = (unsigned)f2b(s[2]) | ((unsigned)f2b(s[3]) << 16);
  o.z = (unsigned)f2b(s[4]) | ((unsigned)f2b(s[5]) << 16);
  o.w = (unsigned)f2b(s[6]) | ((unsigned)f2b(s[7]) << 16);
  return o;
}

// ---------------- gather: x[t,e] = word_embeds[sentence[t], e] ----------------
__global__ void k_gather(const int* __restrict__ sent, const float* __restrict__ we,
                         float* __restrict__ x){
  int idx = blockIdx.x*256 + threadIdx.x;
  if (idx < T_LEN*E_DIM){
    int t = idx / E_DIM, e = idx - t*E_DIM;
    x[idx] = we[(size_t)sent[t]*E_DIM + e];
  }
}

// ---------------- zero the tagged h ring buffer (2 dir * 2 slot * 512 u32) ----
__global__ void k_init(unsigned* __restrict__ hbuf){
  int i = blockIdx.x*256 + threadIdx.x;
  if (i < 2048) hbuf[i] = 0u;  // tag 0, bf16 value +0.0
}

// ---------------- MFMA bf16 GEMM: C = act( A(·rev?) * B^T + bias ) ------------
// (unchanged — verified rounds 3-5)
__global__ __launch_bounds__(256) void k_gemm_mfma(
    const float* __restrict__ Af, int lda, int arev,
    const float* __restrict__ Bf, const unsigned short* __restrict__ Bh, int ldb,
    const float* __restrict__ bias, int act,
    float* __restrict__ C, int ldc, int M, int N, int K)
{
  __shared__ __align__(16) unsigned short As[64*40];
  __shared__ __align__(16) unsigned short Bs[64*40];
  const int tid = threadIdx.x;
  const int bm = blockIdx.y*64, bn = blockIdx.x*64;
  const int r  = tid >> 2, c8 = (tid & 3) * 8;
  const int wave = tid >> 6, lane = tid & 63;
  const int wm = (wave >> 1) * 32, wn = (wave & 1) * 32;
  const int col = lane & 15, quad = lane >> 4;

  const int am = arev ? (M-1-(bm+r)) : (bm+r);
  const float* arow = Af + (size_t)am*lda;
  const float* brow = Bf ? (Bf + (size_t)(bn+r)*ldb) : (const float*)0;
  const unsigned short* brh = Bh ? (Bh + (size_t)(bn+r)*ldb) : (const unsigned short*)0;

  uint4* aw = (uint4*)(As + r*40 + c8);
  uint4* bw = (uint4*)(Bs + r*40 + c8);

  f32x4 acc[2][2];
  #pragma unroll
  for (int i=0;i<2;i++)
    #pragma unroll
    for (int j=0;j<2;j++) acc[i][j] = (f32x4){0.f,0.f,0.f,0.f};

  for (int k0 = 0; k0 < K; k0 += 32){
    uint4 avv, bvv;
    if (k0 + 32 <= K){
      avv = pack8(arow + k0 + c8);
      bvv = Bh ? *(const uint4*)(brh + k0 + c8) : pack8(brow + k0 + c8);
    } else {
      float ta[8], tb[8];
      #pragma unroll
      for (int i=0;i<8;i++){
        const int kk = k0 + c8 + i;
        ta[i] = (kk < K) ? arow[kk] : 0.f;
        tb[i] = (kk < K && Bf) ? brow[kk] : 0.f;
      }
      avv = pack8(ta); bvv = pack8(tb);
    }
    if (k0) __syncthreads();
    *aw = avv; *bw = bvv;
    __syncthreads();
    const short8x a0 = *(const short8x*)(As + (wm+col)*40    + quad*8);
    const short8x a1 = *(const short8x*)(As + (wm+16+col)*40 + quad*8);
    const short8x b0 = *(const short8x*)(Bs + (wn+col)*40    + quad*8);
    const short8x b1 = *(const short8x*)(Bs + (wn+16+col)*40 + quad*8);
    acc[0][0] = __builtin_amdgcn_mfma_f32_16x16x32_bf16(a0, b0, acc[0][0], 0, 0, 0);
    acc[0][1] = __builtin_amdgcn_mfma_f32_16x16x32_bf16(a0, b1, acc[0][1], 0, 0, 0);
    acc[1][0] = __builtin_amdgcn_mfma_f32_16x16x32_bf16(a1, b0, acc[1][0], 0, 0, 0);
    acc[1][1] = __builtin_amdgcn_mfma_f32_16x16x32_bf16(a1, b1, acc[1][1], 0, 0, 0);
  }

  #pragma unroll
  for (int mt=0;mt<2;mt++){
    #pragma unroll
    for (int nt=0;nt<2;nt++){
      const int cc = bn + wn + 16*nt + col;
      const float bs = bias ? bias[cc] : 0.f;
      #pragma unroll
      for (int i=0;i<4;i++){
        const int rr = bm + wm + 16*mt + quad*4 + i;
        float v = acc[mt][nt][i] + bs;
        if (act) v = ftanh(v);
        C[(size_t)rr*ldc + cc] = v;
      }
    }
  }
}

// ======== barrier-free wave-autonomous bidirectional LSTM recurrence ==========
// 256 WGs x 64 threads (1 wave each; trivially all-resident on 256 CUs).
// blocks 0..127: forward, 128..255: backward. Wave wid owns h-units
// base_u = wid*4 .. +3, ALL FOUR GATES: A-tile row m=(gate<<2)|unit ->
// Whh row (col>>2)*512 + base_u + (col&3). MFMA over K=512 = 16 frags.
// The D result (replicated over cols) holds all 4 gates x 4 units -> complete
// cell update stays inside the wave (shfl gather). No LDS, no __syncthreads.
// h exchange: hbuf[dir][slot][512] u32 = (tag<<16)|bf16, published with the
// proven AGENT-scope atomic stores; consumed with 32 wide dwordx4 sc0 sc1
// loads + one vmcnt(0) + batched re-poll of stale chunks.
#define CHUNK_LIST(M) \
  M(0,"0","16")      M(1,"128","144")   M(2,"256","272")   M(3,"384","400")   \
  M(4,"512","528")   M(5,"640","656")   M(6,"768","784")   M(7,"896","912")   \
  M(8,"1024","1040") M(9,"1152","1168") M(10,"1280","1296")M(11,"1408","1424")\
  M(12,"1536","1552")M(13,"1664","1680")M(14,"1792","1808")M(15,"1920","1936")

#define ISSUE_CHUNK(s,O0,O1) \
  asm volatile("global_load_dwordx4 %0, %[p], off offset:" O0 " sc0 sc1\n\t" \
               "global_load_dwordx4 %1, %[p], off offset:" O1 " sc0 sc1" \
               : "=&v"(cl[s]), "=&v"(ch[s]) : [p] "v"(ap) : "memory");

#define RETRY_CHUNK(s,O0,O1) if (mask & (1u<<s)) { ISSUE_CHUNK(s,O0,O1) }

#define CHECK_CHUNK(s,O0,O1) \
  if (!__all(chunk_ok(cl[s], ch[s], tagw))) mask |= (1u<<s);

#define RECHECK_CHUNK(s,O0,O1) \
  if ((mask & (1u<<s)) && !__all(chunk_ok(cl[s], ch[s], tagw))) nm |= (1u<<s);

#define DECODE_MFMA(s,O0,O1) { \
  uint4 pk; \
  pk.x = __builtin_amdgcn_perm(cl[s].y, cl[s].x, 0x05040100u); \
  pk.y = __builtin_amdgcn_perm(cl[s].w, cl[s].z, 0x05040100u); \
  pk.z = __builtin_amdgcn_perm(ch[s].y, ch[s].x, 0x05040100u); \
  pk.w = __builtin_amdgcn_perm(ch[s].w, ch[s].z, 0x05040100u); \
  short8x bb = *reinterpret_cast<short8x*>(&pk); \
  if (s & 1) a1 = __builtin_amdgcn_mfma_f32_16x16x32_bf16(w_frag[s], bb, a1, 0,0,0); \
  else       a0 = __builtin_amdgcn_mfma_f32_16x16x32_bf16(w_frag[s], bb, a0, 0,0,0); }

static __device__ __forceinline__ bool chunk_ok(uint4 a, uint4 b, unsigned tagw){
  unsigned d = (a.x^tagw)|(a.y^tagw)|(a.z^tagw)|(a.w^tagw)
             | (b.x^tagw)|(b.y^tagw)|(b.z^tagw)|(b.w^tagw);
  return (d & 0xFFFF0000u) == 0u;
}

__global__ __launch_bounds__(64, 1) void k_lstm(
    const float* __restrict__ Whh_f, const float* __restrict__ Whh_b,
    const float* __restrict__ bih_f, const float* __restrict__ bhh_f,
    const float* __restrict__ bih_b, const float* __restrict__ bhh_b,
    const float* __restrict__ xg_f, const float* __restrict__ xg_b,
    unsigned* __restrict__ hbuf, float* __restrict__ enc)
{
  const int dir = blockIdx.x >> 7;         // 0 fwd, 1 bwd
  const int wid = blockIdx.x & 127;
  const int base_u = wid*4;                // h-unit base (0..508)
  const int lane = threadIdx.x & 63;
  const int col = lane & 15, quad = lane >> 4;
  const int u = lane & 3;

  const float* Whh = dir ? Whh_b : Whh_f;
  const float* xg  = dir ? xg_b  : xg_f;

  // A-frag preload: row m=col -> (gate=col>>2, unit=col&3)
  const int rowW = (col>>2)*H_DIM + base_u + (col&3);
  const float* wr = Whh + (size_t)rowW*H_DIM;
  short8x w_frag[16];
  #pragma unroll
  for (int s=0;s<16;s++){
    uint4 uu = pack8(wr + s*32 + quad*8);
    w_frag[s] = *reinterpret_cast<short8x*>(&uu);
  }

  // per-lane own (gate=quad, unit=u) bias + xg pipeline
  const int row2 = quad*H_DIM + base_u + u;
  const float bias_r = dir ? (bih_b[row2] + bhh_b[row2]) : (bih_f[row2] + bhh_f[row2]);
  float xg_cur = xg[row2];   // step t=1 uses xg row 0
  float c_reg = 0.f;

  unsigned* hb = hbuf + dir*1024;                    // [2][512]
  const unsigned* ap0 = hb + 0*512 + quad*8;         // slot-0 lane base
  const unsigned* ap1 = hb + 1*512 + quad*8;         // slot-1 lane base

  for (int t = 1; t <= T_LEN; ++t){
    // prefetch next step's xg (covered by the vmcnt(0) below)
    float xg_nxt = 0.f;
    if (t < T_LEN) xg_nxt = xg[(size_t)t*G4 + row2];

    const unsigned* ap = ((t-1)&1) ? ap1 : ap0;
    const unsigned tagw = ((unsigned)(t-1)) << 16;
    uint4 cl[16], ch[16];

    CHUNK_LIST(ISSUE_CHUNK)
    asm volatile("s_waitcnt vmcnt(0)" ::: "memory");

    unsigned mask = 0u;
    CHUNK_LIST(CHECK_CHUNK)
    while (mask){
      CHUNK_LIST(RETRY_CHUNK)
      asm volatile("s_waitcnt vmcnt(0)" ::: "memory");
      unsigned nm = 0u;
      CHUNK_LIST(RECHECK_CHUNK)
      mask = nm;
    }

    f32x4 a0 = (f32x4){0.f,0.f,0.f,0.f}, a1 = (f32x4){0.f,0.f,0.f,0.f};
    CHUNK_LIST(DECODE_MFMA)
    const f32x4 asum = a0 + a1;   // D[m], m=quad*4+i, replicated over cols

    // own pre-activation (gate=quad, unit=u), activate, gather 4 gates by shfl
    const float au  = (u==0)?asum[0]:((u==1)?asum[1]:((u==2)?asum[2]:asum[3]));
    const float val = au + bias_r + xg_cur;
    const float act = (quad==2) ? ftanh(val) : sigm(val);
    const float iv = __shfl(act, u);
    const float fv = __shfl(act, u+16);
    const float gg = __shfl(act, u+32);
    const float ov = __shfl(act, u+48);
    c_reg = fv*c_reg + iv*gg;
    const float hh = ov*ftanh(c_reg);

    if (lane < 4){
      const unsigned pw = ((unsigned)t << 16) | (unsigned)f2b(hh);
      __hip_atomic_store(hb + (t&1)*512 + base_u + lane, pw,
                         __ATOMIC_RELAXED, __HIP_MEMORY_SCOPE_AGENT);
      const int tt = dir ? (T_LEN - t) : (t - 1);
      enc[(size_t)tt*D_DIM + dir*H_DIM + base_u + lane] = hh;
    }
    xg_cur = xg_nxt;
  }
}

// ---------------- row softmax in place, rows of 1024 --------------------------
__global__ __launch_bounds__(256) void k_softmax(float* __restrict__ S){
  float* r = S + (size_t)blockIdx.x*1024;
  const int tid = threadIdx.x;
  float v[4];
  #pragma unroll
  for (int i=0;i<4;i++) v[i] = r[tid + i*256];
  float m = fmaxf(fmaxf(v[0],v[1]), fmaxf(v[2],v[3]));
  #pragma unroll
  for (int off=32; off>=1; off>>=1) m = fmaxf(m, __shfl_xor(m, off));
  __shared__ float red[4], red2[4];
  const int wid = tid >> 6, lane = tid & 63;
  if (lane == 0) red[wid] = m;
  __syncthreads();
  m = fmaxf(fmaxf(red[0],red[1]), fmaxf(red[2],red[3]));
  float s = 0.f;
  #pragma unroll
  for (int i=0;i<4;i++){ v[i] = __expf(v[i]-m); s += v[i]; }
  #pragma unroll
  for (int off=32; off>=1; off>>=1) s += __shfl_xor(s, off);
  if (lane == 0) red2[wid] = s;
  __syncthreads();
  s = red2[0]+red2[1]+red2[2]+red2[3];
  const float inv = frcp(s);
  #pragma unroll
  for (int i=0;i<4;i++) r[tid + i*256] = v[i]*inv;
}

// ---------------- copy enc into cat[:, 0:1024] (f32) --------------------------
__global__ void k_copy_enc(const float* __restrict__ enc, float* __restrict__ cat){
  int idx = blockIdx.x*256 + threadIdx.x;
  if (idx < T_LEN*D_DIM){
    int t = idx >> 10, d = idx & 1023;
    cat[(size_t)t*2048 + d] = enc[idx];
  }
}

// ---------------- transpose-cast: encT_bf16[d][t] = bf16(enc[t][d]) -----------
__global__ __launch_bounds__(256) void k_castT(const float* __restrict__ src,
                                               unsigned short* __restrict__ dst){
  __shared__ float tile[32][33];
  const int bx = blockIdx.x*32, by = blockIdx.y*32;
  const int tx = threadIdx.x & 31, ty8 = threadIdx.x >> 5;
  #pragma unroll
  for (int i=ty8;i<32;i+=8) tile[i][tx] = src[(size_t)(by+i)*1024 + bx+tx];
  __syncthreads();
  #pragma unroll
  for (int i=ty8;i<32;i+=8) dst[(size_t)(bx+i)*1024 + by+tx] = f2b(tile[tx][i]);
}

// ---------------- feats = h1 * tag_W^T + tag_b  [1024,12] ---------------------
__global__ __launch_bounds__(256) void k_feats(
    const float* __restrict__ h1, const float* __restrict__ tagW,
    const float* __restrict__ tagb, float* __restrict__ feats)
{
  const int t = blockIdx.x;
  const int wave = threadIdx.x >> 6, lane = threadIdx.x & 63;
  const float* hr = h1 + (size_t)t*D_DIM;
  float hv[16];
  #pragma unroll
  for (int i=0;i<16;i++) hv[i] = hr[lane + 64*i];
  #pragma unroll
  for (int j=0;j<3;j++){
    const int tag = wave*3 + j;
    const float* wr = tagW + (size_t)tag*D_DIM;
    float s = 0.f;
    #pragma unroll
    for (int i=0;i<16;i++) s += hv[i]*wr[lane + 64*i];
    #pragma unroll
    for (int off=32; off>=1; off>>=1) s += __shfl_xor(s, off);
    if (lane == 0) feats[(size_t)t*K_TAGS + tag] = s + tagb[tag];
  }
}

// ---------------- CRF forward + gold score, single wave -----------------------
// feats staged through LDS in 64-timestep blocks (coalesced, off serial chain)
__global__ void k_crf(const float* __restrict__ feats, const float* __restrict__ trans,
                      const int* __restrict__ tags, float* __restrict__ out){
  const int tid = threadIdx.x;  // 64 threads, one wave
  __shared__ float fs[768];
  float gold = 0.f;
  for (int i = tid; i <= T_LEN; i += 64){
    const int to = (i < T_LEN) ? tags[i]   : 11;        // STOP
    const int fr = (i == 0)    ? 10        : tags[i-1]; // START
    gold += trans[to*K_TAGS + fr];
    if (i < T_LEN) gold += feats[(size_t)i*K_TAGS + tags[i]];
  }
  #pragma unroll
  for (int off=32; off>=1; off>>=1) gold += __shfl_xor(gold, off);

  float Trow[K_TAGS];
  if (tid < K_TAGS){
    #pragma unroll
    for (int j=0;j<K_TAGS;j++) Trow[j] = trans[tid*K_TAGS + j];
  }
  float alpha = (tid == 10) ? 0.f : -10000.f;
  for (int b=0;b<16;++b){
    #pragma unroll
    for (int r=0;r<12;r++) fs[tid + 64*r] = feats[b*768 + tid + 64*r];
    __syncthreads();
    for (int k=0;k<64;++k){
      float av[K_TAGS];
      #pragma unroll
      for (int j=0;j<K_TAGS;j++) av[j] = __shfl(alpha, j);
      if (tid < K_TAGS){
        float vv[K_TAGS], m = -1e30f;
        #pragma unroll
        for (int j=0;j<K_TAGS;j++){ vv[j] = av[j] + Trow[j]; m = fmaxf(m, vv[j]); }
        float s = 0.f;
        #pragma unroll
        for (int j=0;j<K_TAGS;j++) s += __expf(vv[j]-m);
        alpha = m + __logf(s) + fs[k*K_TAGS + tid];
      }
    }
    __syncthreads();
  }
  float v = (tid < K_TAGS) ? (alpha + trans[11*K_TAGS + tid]) : -1e30f;
  float m = v;
  #pragma unroll
  for (int off=32; off>=1; off>>=1) m = fmaxf(m, __shfl_xor(m, off));
  float e = (tid < K_TAGS) ? __expf(v - m) : 0.f;
  #pragma unroll
  for (int off=32; off>=1; off>>=1) e += __shfl_xor(e, off);
  if (tid == 0) out[0] = (m + __logf(e)) - gold;
}

// ------------------------------------------------------------------------------
extern "C" void kernel_launch(void* const* d_in, const int* in_sizes, int n_in,
                              void* d_out, int out_size, void* d_ws, size_t ws_size,
                              hipStream_t stream)
{
  const int*   sentence = (const int*)d_in[0];
  const int*   tags     = (const int*)d_in[1];
  const float* we       = (const float*)d_in[2];
  const float* Wih_f    = (const float*)d_in[3];
  const float* Whh_f    = (const float*)d_in[4];
  const float* bih_f    = (const float*)d_in[5];
  const float* bhh_f    = (const float*)d_in[6];
  const float* Wih_b    = (const float*)d_in[7];
  const float* Whh_b    = (const float*)d_in[8];
  const float* bih_b    = (const float*)d_in[9];
  const float* bhh_b    = (const float*)d_in[10];
  const float* attn_W   = (const float*)d_in[11];
  const float* attn_b   = (const float*)d_in[12];
  const float* h2h1_W   = (const float*)d_in[13];
  const float* h2h1_b   = (const float*)d_in[14];
  const float* tag_W    = (const float*)d_in[15];
  const float* tag_b    = (const float*)d_in[16];
  const float* trans    = (const float*)d_in[17];
  float* out = (float*)d_out;

  float* ws     = (float*)d_ws;
  float* cat    = ws;                  // [1024,2048]   also xg_f
  float* reg2   = cat  + 2097152;      // [2M]          xg_b; later scores+h1
  float* enc    = reg2 + 2097152;      // [1024,1024]
  float* proj   = enc  + 1048576;      // [1024,1024]   also x; later encT_bf16
  float* feats  = proj + 1048576;      // [1024,12]
  unsigned* hbuf= (unsigned*)(feats + 12288);  // 2048 u32
  float* xg_f   = cat;
  float* xg_b   = reg2;
  float* scores = reg2;
  float* h1     = reg2 + 1048576;
  float* x      = proj;
  unsigned short* encT = (unsigned short*)proj;

  k_gather<<<dim3((T_LEN*E_DIM + 255)/256), dim3(256), 0, stream>>>(sentence, we, x);
  k_init<<<dim3(8), dim3(256), 0, stream>>>(hbuf);
  k_gemm_mfma<<<dim3(32,16), dim3(256), 0, stream>>>(x, E_DIM, 0,
      Wih_f, nullptr, E_DIM, nullptr, 0, xg_f, G4, T_LEN, G4, E_DIM);
  k_gemm_mfma<<<dim3(32,16), dim3(256), 0, stream>>>(x, E_DIM, 1,
      Wih_b, nullptr, E_DIM, nullptr, 0, xg_b, G4, T_LEN, G4, E_DIM);
  k_lstm<<<dim3(256), dim3(64), 0, stream>>>(Whh_f, Whh_b, bih_f, bhh_f,
      bih_b, bhh_b, xg_f, xg_b, hbuf, enc);
  k_gemm_mfma<<<dim3(16,16), dim3(256), 0, stream>>>(enc, D_DIM, 0,
      attn_W, nullptr, D_DIM, attn_b, 0, proj, D_DIM, T_LEN, D_DIM, D_DIM);
  k_gemm_mfma<<<dim3(16,16), dim3(256), 0, stream>>>(enc, D_DIM, 0,
      proj, nullptr, D_DIM, nullptr, 0, scores, T_LEN, T_LEN, T_LEN, D_DIM);
  k_softmax<<<dim3(1024), dim3(256), 0, stream>>>(scores);
  k_copy_enc<<<dim3(4096), dim3(256), 0, stream>>>(enc, cat);
  k_castT<<<dim3(32,32), dim3(256), 0, stream>>>(enc, encT);
  k_gemm_mfma<<<dim3(16,16), dim3(256), 0, stream>>>(scores, T_LEN, 0,
      nullptr, encT, D_DIM, nullptr, 0, cat + 1024, 2048, T_LEN, D_DIM, T_LEN);
  k_gemm_mfma<<<dim3(16,16), dim3(256), 0, stream>>>(cat, 2048, 0,
      h2h1_W, nullptr, 2048, h2h1_b, 1, h1, D_DIM, T_LEN, D_DIM, 2048);
  k_feats<<<dim3(1024), dim3(256), 0, stream>>>(h1, tag_W, tag_b, feats);
  k_crf<<<dim3(1), dim3(64), 0, stream>>>(feats, trans, tags, out);
}